// Round 12
// baseline (258.520 us; speedup 1.0000x reference)
//
#include <hip/hip_runtime.h>

#define N_NODES 50000
#define N_EDGES 800000
#define C_IN 128
#define C_HID 256
#define C_OUT 128
#define BN_EPS 1e-5f

typedef __bf16 v8bf __attribute__((ext_vector_type(8)));
typedef float f32x4 __attribute__((ext_vector_type(4)));
typedef unsigned short u16x8 __attribute__((ext_vector_type(8)));

// ---------- bf16 helpers (round-to-nearest-even) ----------
static __device__ __forceinline__ unsigned short f2bf(float f) {
    unsigned int u = __float_as_uint(f);
    u += 0x7fffu + ((u >> 16) & 1u);
    return (unsigned short)(u >> 16);
}
static __device__ __forceinline__ float bf2f(unsigned short h) {
    return __uint_as_float((unsigned int)h << 16);
}
static __device__ __forceinline__ unsigned int pack2(float a, float b) {
    return (unsigned int)f2bf(a) | ((unsigned int)f2bf(b) << 16);
}
static __device__ __forceinline__ float lo2f(unsigned int u) { return __uint_as_float(u << 16); }
static __device__ __forceinline__ float hi2f(unsigned int u) { return __uint_as_float(u & 0xffff0000u); }

#define DEG_BLOCKS ((N_EDGES + 255) / 256)
#define CAST_BLOCKS ((N_NODES * 16 + 255) / 256)   // 3125: x -> bf16 cast, 8 floats/thread

// ---------------- degree + rank + weight transpose + UNSCALED x cast (fused) ----------
// 800k device-scope atomics: bound by per-atomic memory-side cost (round-9: counter
// splitting neutral), not line contention. The x cast rides the idle BW.

__global__ __launch_bounds__(256) void k_deg_wtrans(const int* __restrict__ dst, int* __restrict__ deg4,
                                                    int* __restrict__ rank,
                                                    const float* __restrict__ W1, const float* __restrict__ W2,
                                                    unsigned short* __restrict__ WT1, unsigned short* __restrict__ WT2,
                                                    const float* __restrict__ x, unsigned short* __restrict__ xb) {
    int bx = blockIdx.x, t = threadIdx.x;
    if (bx < DEG_BLOCKS) {
        int e = bx * 256 + t;
        if (e < N_EDGES) {
            int s = e & 3;
            rank[e] = atomicAdd(&deg4[s * N_NODES + dst[e]], 1);
        }
    } else if (bx < DEG_BLOCKS + 256) {
        int i = (bx - DEG_BLOCKS) * 256 + t;  // [0, 65536)
        if (i < C_IN * C_HID) {               // WT1[n][k] = W1[k][n]
            int n = i >> 7, k = i & 127;
            WT1[n * C_IN + k] = f2bf(W1[k * C_HID + n]);
        } else {
            int j = i - C_IN * C_HID;         // WT2[n][k] = W2[k][n]
            int n = j >> 8, k = j & 255;
            WT2[n * C_HID + k] = f2bf(W2[k * C_OUT + n]);
        }
    } else {
        int i = (bx - DEG_BLOCKS - 256) * 256 + t;
        int node = i >> 4;
        if (node < N_NODES) {
            int g8 = (i & 15) * 8;
            float4 v0 = *(const float4*)&x[(size_t)node * C_IN + g8];
            float4 v1 = *(const float4*)&x[(size_t)node * C_IN + g8 + 4];
            uint4 o = make_uint4(pack2(v0.x, v0.y), pack2(v0.z, v0.w),
                                 pack2(v1.x, v1.y), pack2(v1.z, v1.w));
            *(uint4*)&xb[(size_t)node * C_IN + g8] = o;
        }
    }
}

// ---------------- CSR build ----------------

__global__ __launch_bounds__(512) void k_scan1(int* __restrict__ deg4, int* __restrict__ rs,
                                               int* __restrict__ partial, float* __restrict__ dis) {
    __shared__ int s[512];
    int t = threadIdx.x;
    int i = blockIdx.x * 512 + t;
    int v = 0;
    if (i < N_NODES) {
        int d0 = deg4[i];
        int d1 = deg4[N_NODES + i];
        int d2 = deg4[2 * N_NODES + i];
        int d3 = deg4[3 * N_NODES + i];
        v = d0 + d1 + d2 + d3;
        deg4[N_NODES + i] = d0;
        deg4[2 * N_NODES + i] = d0 + d1;
        deg4[3 * N_NODES + i] = d0 + d1 + d2;
        dis[i] = rsqrtf((float)v + 1.0f);
    }
    s[t] = v;
    __syncthreads();
    for (int off = 1; off < 512; off <<= 1) {
        int tv = (t >= off) ? s[t - off] : 0;
        __syncthreads();
        s[t] += tv;
        __syncthreads();
    }
    if (i < N_NODES) rs[i + 1] = s[t];
    if (t == 511) partial[blockIdx.x] = s[511];
}

// fused scan2+scan3
__global__ __launch_bounds__(256) void k_scan23(int* __restrict__ rs, const int* __restrict__ partial,
                                                int nb) {
    __shared__ int pre[128];
    __shared__ int wsum[2];
    int t = threadIdx.x;
    int lane = t & 63;
    int pv = 0, v = 0;
    if (t < 128) {
        pv = (t < nb) ? partial[t] : 0;
        v = pv;
#pragma unroll
        for (int off = 1; off < 64; off <<= 1) {
            int u = __shfl_up(v, off);
            if (lane >= off) v += u;
        }
        if (lane == 63) wsum[t >> 6] = v;
    }
    __syncthreads();
    if (t < 128) {
        if (t >= 64) v += wsum[0];
        pre[t] = v - pv;
    }
    __syncthreads();
    int i = blockIdx.x * 256 + t;
    if (i < N_NODES) {
        rs[i + 1] = rs[i + 1] + pre[i >> 9];
    }
    if (i == 0) rs[0] = 0;
}

// ---------------- atomic-free CSR placement (split-prefix aware) ----------------

#define PLACE_BLOCKS ((N_EDGES / 4 + 255) / 256)   // 800000/4 lanes of int4

__global__ __launch_bounds__(256) void k_place(const int* __restrict__ src, const int* __restrict__ dst,
                                               const int* __restrict__ rank, const int* __restrict__ rs,
                                               const int* __restrict__ deg4, int* __restrict__ eidx) {
    int q = blockIdx.x * 256 + threadIdx.x;
    int e = q * 4;
    if (e < N_EDGES) {
        int4 d4 = *(const int4*)&dst[e];
        int4 r4 = *(const int4*)&rank[e];
        int4 s4 = *(const int4*)&src[e];
        eidx[rs[d4.x] + r4.x] = s4.x;
        eidx[rs[d4.y] + deg4[N_NODES + d4.y] + r4.y] = s4.y;
        eidx[rs[d4.z] + deg4[2 * N_NODES + d4.z] + r4.z] = s4.z;
        eidx[rs[d4.w] + deg4[3 * N_NODES + d4.w] + r4.w] = s4.w;
    }
}

// ---------------- 128-ch row aggregate: one wave per node (round-7 structure) -------

template <bool FINAL>
__global__ __launch_bounds__(256) void k_aggr(const unsigned short* __restrict__ g,
                                              const float* __restrict__ dis, const float* __restrict__ bias,
                                              const int* __restrict__ rs, const int* __restrict__ eidx,
                                              unsigned short* __restrict__ outb, float* __restrict__ outf) {
    int wid = (blockIdx.x * 256 + threadIdx.x) >> 6;
    int lane = threadIdx.x & 63;
    if (wid >= N_NODES) return;
    int slot = lane >> 4;        // 0..3: which edge of a 4-group
    int cp = lane & 15;          // channel group: 8 ch starting at cp*8
    int s = rs[wid], e = rs[wid + 1];
    float a0 = 0.f, a1 = 0.f, a2 = 0.f, a3 = 0.f, a4 = 0.f, a5 = 0.f, a6 = 0.f, a7 = 0.f;
    int p = s;
    for (; p + 15 < e; p += 16) {
        int i0 = eidx[p + slot];
        int i1 = eidx[p + 4 + slot];
        int i2 = eidx[p + 8 + slot];
        int i3 = eidx[p + 12 + slot];
        u16x8 v0 = *(const u16x8*)&g[(size_t)i0 * 128 + cp * 8];
        u16x8 v1 = *(const u16x8*)&g[(size_t)i1 * 128 + cp * 8];
        u16x8 v2 = *(const u16x8*)&g[(size_t)i2 * 128 + cp * 8];
        u16x8 v3 = *(const u16x8*)&g[(size_t)i3 * 128 + cp * 8];
        if (FINAL) {
            a0 += bf2f(v0[0]) + bf2f(v1[0]) + bf2f(v2[0]) + bf2f(v3[0]);
            a1 += bf2f(v0[1]) + bf2f(v1[1]) + bf2f(v2[1]) + bf2f(v3[1]);
            a2 += bf2f(v0[2]) + bf2f(v1[2]) + bf2f(v2[2]) + bf2f(v3[2]);
            a3 += bf2f(v0[3]) + bf2f(v1[3]) + bf2f(v2[3]) + bf2f(v3[3]);
            a4 += bf2f(v0[4]) + bf2f(v1[4]) + bf2f(v2[4]) + bf2f(v3[4]);
            a5 += bf2f(v0[5]) + bf2f(v1[5]) + bf2f(v2[5]) + bf2f(v3[5]);
            a6 += bf2f(v0[6]) + bf2f(v1[6]) + bf2f(v2[6]) + bf2f(v3[6]);
            a7 += bf2f(v0[7]) + bf2f(v1[7]) + bf2f(v2[7]) + bf2f(v3[7]);
        } else {
            float w0 = dis[i0], w1 = dis[i1], w2 = dis[i2], w3 = dis[i3];
            a0 = fmaf(w0, bf2f(v0[0]), fmaf(w1, bf2f(v1[0]), fmaf(w2, bf2f(v2[0]), fmaf(w3, bf2f(v3[0]), a0))));
            a1 = fmaf(w0, bf2f(v0[1]), fmaf(w1, bf2f(v1[1]), fmaf(w2, bf2f(v2[1]), fmaf(w3, bf2f(v3[1]), a1))));
            a2 = fmaf(w0, bf2f(v0[2]), fmaf(w1, bf2f(v1[2]), fmaf(w2, bf2f(v2[2]), fmaf(w3, bf2f(v3[2]), a2))));
            a3 = fmaf(w0, bf2f(v0[3]), fmaf(w1, bf2f(v1[3]), fmaf(w2, bf2f(v2[3]), fmaf(w3, bf2f(v3[3]), a3))));
            a4 = fmaf(w0, bf2f(v0[4]), fmaf(w1, bf2f(v1[4]), fmaf(w2, bf2f(v2[4]), fmaf(w3, bf2f(v3[4]), a4))));
            a5 = fmaf(w0, bf2f(v0[5]), fmaf(w1, bf2f(v1[5]), fmaf(w2, bf2f(v2[5]), fmaf(w3, bf2f(v3[5]), a5))));
            a6 = fmaf(w0, bf2f(v0[6]), fmaf(w1, bf2f(v1[6]), fmaf(w2, bf2f(v2[6]), fmaf(w3, bf2f(v3[6]), a6))));
            a7 = fmaf(w0, bf2f(v0[7]), fmaf(w1, bf2f(v1[7]), fmaf(w2, bf2f(v2[7]), fmaf(w3, bf2f(v3[7]), a7))));
        }
    }
    if (p < e) {
        int last = e - 1;
        int j0 = p + slot;
        int j1 = j0 + 4;
        int j2 = j0 + 8;
        int j3 = j0 + 12;
        float m0 = (j0 <= last) ? 1.f : 0.f;
        float m1 = (j1 <= last) ? 1.f : 0.f;
        float m2 = (j2 <= last) ? 1.f : 0.f;
        float m3 = (j3 <= last) ? 1.f : 0.f;
        j0 = min(j0, last); j1 = min(j1, last); j2 = min(j2, last); j3 = min(j3, last);
        int i0 = eidx[j0];
        int i1 = eidx[j1];
        int i2 = eidx[j2];
        int i3 = eidx[j3];
        float w0 = m0, w1 = m1, w2 = m2, w3 = m3;
        if (!FINAL) {
            w0 = m0 * dis[i0]; w1 = m1 * dis[i1]; w2 = m2 * dis[i2]; w3 = m3 * dis[i3];
        }
        u16x8 v0 = *(const u16x8*)&g[(size_t)i0 * 128 + cp * 8];
        u16x8 v1 = *(const u16x8*)&g[(size_t)i1 * 128 + cp * 8];
        u16x8 v2 = *(const u16x8*)&g[(size_t)i2 * 128 + cp * 8];
        u16x8 v3 = *(const u16x8*)&g[(size_t)i3 * 128 + cp * 8];
        a0 = fmaf(w0, bf2f(v0[0]), fmaf(w1, bf2f(v1[0]), fmaf(w2, bf2f(v2[0]), fmaf(w3, bf2f(v3[0]), a0))));
        a1 = fmaf(w0, bf2f(v0[1]), fmaf(w1, bf2f(v1[1]), fmaf(w2, bf2f(v2[1]), fmaf(w3, bf2f(v3[1]), a1))));
        a2 = fmaf(w0, bf2f(v0[2]), fmaf(w1, bf2f(v1[2]), fmaf(w2, bf2f(v2[2]), fmaf(w3, bf2f(v3[2]), a2))));
        a3 = fmaf(w0, bf2f(v0[3]), fmaf(w1, bf2f(v1[3]), fmaf(w2, bf2f(v2[3]), fmaf(w3, bf2f(v3[3]), a3))));
        a4 = fmaf(w0, bf2f(v0[4]), fmaf(w1, bf2f(v1[4]), fmaf(w2, bf2f(v2[4]), fmaf(w3, bf2f(v3[4]), a4))));
        a5 = fmaf(w0, bf2f(v0[5]), fmaf(w1, bf2f(v1[5]), fmaf(w2, bf2f(v2[5]), fmaf(w3, bf2f(v3[5]), a5))));
        a6 = fmaf(w0, bf2f(v0[6]), fmaf(w1, bf2f(v1[6]), fmaf(w2, bf2f(v2[6]), fmaf(w3, bf2f(v3[6]), a6))));
        a7 = fmaf(w0, bf2f(v0[7]), fmaf(w1, bf2f(v1[7]), fmaf(w2, bf2f(v2[7]), fmaf(w3, bf2f(v3[7]), a7))));
    }
    a0 += __shfl_xor(a0, 16); a1 += __shfl_xor(a1, 16); a2 += __shfl_xor(a2, 16); a3 += __shfl_xor(a3, 16);
    a4 += __shfl_xor(a4, 16); a5 += __shfl_xor(a5, 16); a6 += __shfl_xor(a6, 16); a7 += __shfl_xor(a7, 16);
    a0 += __shfl_xor(a0, 32); a1 += __shfl_xor(a1, 32); a2 += __shfl_xor(a2, 32); a3 += __shfl_xor(a3, 32);
    a4 += __shfl_xor(a4, 32); a5 += __shfl_xor(a5, 32); a6 += __shfl_xor(a6, 32); a7 += __shfl_xor(a7, 32);
    if (slot < 2) {
        int ch = cp * 8 + slot * 4;
        float r0 = slot ? a4 : a0, r1 = slot ? a5 : a1, r2 = slot ? a6 : a2, r3 = slot ? a7 : a3;
        ushort4 gi = *(const ushort4*)&g[(size_t)wid * 128 + ch];
        float d = dis[wid];
        if (FINAL) {
            float4 bv = *(const float4*)&bias[ch];
            float4 o = make_float4(fmaf(d, r0 + bf2f(gi.x), bv.x), fmaf(d, r1 + bf2f(gi.y), bv.y),
                                   fmaf(d, r2 + bf2f(gi.z), bv.z), fmaf(d, r3 + bf2f(gi.w), bv.w));
            *(float4*)&outf[(size_t)wid * 128 + ch] = o;
        } else {
            float d2 = d * d;   // z = d*a + d^2 * x_d  (x rows unscaled)
            ushort4 z;
            z.x = f2bf(fmaf(d, r0, d2 * bf2f(gi.x)));
            z.y = f2bf(fmaf(d, r1, d2 * bf2f(gi.y)));
            z.z = f2bf(fmaf(d, r2, d2 * bf2f(gi.z)));
            z.w = f2bf(fmaf(d, r3, d2 * bf2f(gi.w)));
            *(ushort4*)&outb[(size_t)wid * 128 + ch] = z;
        }
    }
}

// ---------------- MFMA bf16 GEMM, register-B panels (round-9 structure) ----------------
// Round-11 lesson: bundled Ct-dbuf + per-strip prefetch on BOTH GEMMs regressed
// (suspect: GEMM2 KC=8 register blowout past the 256-VGPR occupancy step).
// This round: round-9 GEMM verbatim, EXCEPT KC<=4 (GEMM1) pre-loads ALL 4 strips' A-rows
// at wave entry (64 VGPRs, total ~180 < 256 -> occupancy intact). All 16 A-loads in
// flight before the first MFMA: no strip heads on a serial L2/L3 round-trip (round-10
// counters showed GEMM is idle-wave latency-serialization: MfmaUtil 2.5%, occ 6.5%).
// GEMM2 (KC=8) unchanged (B-frags already hold 128 VGPRs; no budget for prefetch).

template <bool TRANS, int KC>   // K = KC*32
__global__ __launch_bounds__(256, 2) void k_gemmv(const unsigned short* __restrict__ Ah,
                                                  const unsigned short* __restrict__ BT,
                                                  unsigned short* __restrict__ C,
                                                  const float* __restrict__ dis, const float* __restrict__ bias,
                                                  float* __restrict__ bnsum, float* __restrict__ bnsq,
                                                  const float* __restrict__ gamma, const float* __restrict__ beta,
                                                  int M, int N) {
    constexpr int K = KC * 32;
    constexpr int BP = K + 8;                   // B LDS pitch (ushorts); rows 16B-aligned
    constexpr bool PREF = (KC <= 4);            // full-depth A prefetch (GEMM1 only)
    __shared__ unsigned short Blds[64 * BP];    // aliased as per-wave C-tiles after extraction
    __shared__ float tsc_s[K];
    __shared__ float tof_s[K];

    int t = threadIdx.x;
    int w = t >> 6, lane = t & 63;
    int lm = lane & 15, quad = lane >> 4;
    int col0 = blockIdx.y * 64;

    if (TRANS && t < K) {
        float inv_n = 1.0f / (float)N_NODES;
        float mu = bnsum[t] * inv_n;
        float var = bnsq[t] * inv_n - mu * mu;
        float a = gamma[t] * rsqrtf(var + BN_EPS);
        tsc_s[t] = a;
        tof_s[t] = beta[t] - mu * a;
    }
    // stage B panel (64 cols x K) to LDS
    constexpr int NLD = 64 * K / 8;
    for (int j = t; j < NLD; j += 256) {
        int n = j / (K / 8);
        int kq = j % (K / 8);
        *(uint4*)&Blds[n * BP + kq * 8] = *(const uint4*)&BT[(size_t)(col0 + n) * K + kq * 8];
    }
    __syncthreads();
    // extract B fragments to registers (row stride BP: 2-way bank alias, free)
    v8bf bfr[4][KC];
#pragma unroll
    for (int in = 0; in < 4; ++in)
#pragma unroll
        for (int kc = 0; kc < KC; ++kc)
            bfr[in][kc] = *(const v8bf*)&Blds[(in * 16 + lm) * BP + kc * 32 + quad * 8];
    __syncthreads();    // B reads done; Blds becomes C-tile scratch

    unsigned short* Ct = Blds + w * (16 * 80);  // per-wave 16x64 tile, pitch 80 (quad-conflict-free)

    float bias_r[4];
    if (!TRANS) {
#pragma unroll
        for (int in = 0; in < 4; ++in) bias_r[in] = bias[col0 + in * 16 + lm];
    }
    float ss[4] = {0.f, 0.f, 0.f, 0.f}, qq[4] = {0.f, 0.f, 0.f, 0.f};

    int strip0 = (blockIdx.x * 4 + w) * 4;
    uint4 apre[PREF ? 4 : 1][KC];
    if constexpr (PREF) {
#pragma unroll
        for (int s = 0; s < 4; ++s) {
            int strip = strip0 + s;
            if (strip * 16 < M) {
#pragma unroll
                for (int kc = 0; kc < KC; ++kc)
                    apre[s][kc] = *(const uint4*)&Ah[(size_t)(strip * 16 + lm) * K + kc * 32 + quad * 8];
            }
        }
    }
#pragma unroll
    for (int s = 0; s < 4; ++s) {
        int strip = strip0 + s;
        if (strip * 16 >= M) break;             // M is a multiple of 16
        int arow = strip * 16 + lm;
        uint4 araw[KC];
        if constexpr (PREF) {
#pragma unroll
            for (int kc = 0; kc < KC; ++kc) araw[kc] = apre[s][kc];
        } else {
#pragma unroll
            for (int kc = 0; kc < KC; ++kc)
                araw[kc] = *(const uint4*)&Ah[(size_t)arow * K + kc * 32 + quad * 8];
        }
        float dqa[4];
        if (TRANS) *(float4*)dqa = *(const float4*)&dis[strip * 16 + quad * 4];
        f32x4 acc[4] = {};
#pragma unroll
        for (int kc = 0; kc < KC; ++kc) {
            v8bf af;
            if (TRANS) {
                int kb2 = kc * 32 + quad * 8;
                float4 s0 = *(const float4*)&tsc_s[kb2];
                float4 s1 = *(const float4*)&tsc_s[kb2 + 4];
                float4 o0 = *(const float4*)&tof_s[kb2];
                float4 o1 = *(const float4*)&tof_s[kb2 + 4];
                uint4 h = araw[kc];
                float f0 = fmaxf(fmaf(lo2f(h.x), s0.x, o0.x), 0.f);
                float f1 = fmaxf(fmaf(hi2f(h.x), s0.y, o0.y), 0.f);
                float f2 = fmaxf(fmaf(lo2f(h.y), s0.z, o0.z), 0.f);
                float f3 = fmaxf(fmaf(hi2f(h.y), s0.w, o0.w), 0.f);
                float f4 = fmaxf(fmaf(lo2f(h.z), s1.x, o1.x), 0.f);
                float f5 = fmaxf(fmaf(hi2f(h.z), s1.y, o1.y), 0.f);
                float f6 = fmaxf(fmaf(lo2f(h.w), s1.z, o1.z), 0.f);
                float f7 = fmaxf(fmaf(hi2f(h.w), s1.w, o1.w), 0.f);
                uint4 pk = make_uint4(pack2(f0, f1), pack2(f2, f3), pack2(f4, f5), pack2(f6, f7));
                af = *(v8bf*)&pk;
            } else {
                af = *(v8bf*)&araw[kc];
            }
#pragma unroll
            for (int in = 0; in < 4; ++in)
                acc[in] = __builtin_amdgcn_mfma_f32_16x16x32_bf16(af, bfr[in][kc], acc[in], 0, 0, 0);
        }
        // epilogue: pack into per-wave LDS tile (C/D layout: row=quad*4+q, col=in*16+lm)
#pragma unroll
        for (int in = 0; in < 4; ++in) {
#pragma unroll
            for (int q = 0; q < 4; ++q) {
                float val = TRANS ? acc[in][q] * dqa[q] : acc[in][q] + bias_r[in];
                unsigned short hb = f2bf(val);
                Ct[(quad * 4 + q) * 80 + in * 16 + lm] = hb;
                if (!TRANS) {
                    float v = bf2f(hb);
                    ss[in] += v;
                    qq[in] = fmaf(v, v, qq[in]);
                }
            }
        }
        // same-wave LDS round trip (in-order, no barrier) -> coalesced 16B stores
#pragma unroll
        for (int it = 0; it < 2; ++it) {
            int rl = (lane >> 3) + it * 8;
            uint4 v = *(const uint4*)&Ct[rl * 80 + (lane & 7) * 8];
            *(uint4*)&C[(size_t)(strip * 16 + rl) * N + col0 + (lane & 7) * 8] = v;
        }
    }
    if (!TRANS) {
#pragma unroll
        for (int in = 0; in < 4; ++in) {
            float s = ss[in], q2 = qq[in];
            s += __shfl_xor(s, 16); q2 += __shfl_xor(q2, 16);
            s += __shfl_xor(s, 32); q2 += __shfl_xor(q2, 32);
            if (quad == 0) {
                atomicAdd(&bnsum[col0 + in * 16 + lm], s);
                atomicAdd(&bnsq[col0 + in * 16 + lm], q2);
            }
        }
    }
}

// ---------------- launch ----------------

extern "C" void kernel_launch(void* const* d_in, const int* in_sizes, int n_in,
                              void* d_out, int out_size, void* d_ws, size_t ws_size,
                              hipStream_t stream) {
    const float* x      = (const float*)d_in[0];
    const int*   ei     = (const int*)d_in[1];
    const float* W1     = (const float*)d_in[2];
    const float* b1     = (const float*)d_in[3];
    const float* gamma1 = (const float*)d_in[4];
    const float* beta1  = (const float*)d_in[5];
    const float* W2     = (const float*)d_in[6];
    const float* b2     = (const float*)d_in[7];
    const int* srcv = ei;
    const int* dstv = ei + N_EDGES;
    float* out = (float*)d_out;

    char* w = (char*)d_ws;
    size_t off = 0;
    auto alloc = [&](size_t bytes) {
        void* p = w + off;
        off = (off + bytes + 255) & ~(size_t)255;
        return p;
    };
    int*   deg4    = (int*)alloc((size_t)N_NODES * 4 * 4);   // 4 split counters / prefix offsets
    float* bnsum   = (float*)alloc(256 * 4);
    float* bnsq    = (float*)alloc(256 * 4);
    size_t zero_bytes = off;                           // deg4 + bnsum + bnsq
    float* dis     = (float*)alloc(N_NODES * 4);
    int*   rs      = (int*)alloc((N_NODES + 1) * 4);
    int*   rank    = (int*)alloc((size_t)N_EDGES * 4);
    int*   partial = (int*)alloc(128 * 4);
    int*   eidx    = (int*)alloc((size_t)N_EDGES * 4);
    unsigned short* WT1 = (unsigned short*)alloc((size_t)C_IN * C_HID * 2);
    unsigned short* WT2 = (unsigned short*)alloc((size_t)C_HID * C_OUT * 2);
    unsigned short* xb  = (unsigned short*)alloc((size_t)N_NODES * C_IN * 2);
    unsigned short* P   = (unsigned short*)alloc((size_t)N_NODES * C_IN * 2);
    unsigned short* z1  = (unsigned short*)alloc((size_t)N_NODES * C_HID * 2);
    unsigned short* g2  = (unsigned short*)alloc((size_t)N_NODES * C_OUT * 2);
    (void)ws_size; (void)in_sizes; (void)n_in; (void)out_size;

    (void)hipMemsetAsync(deg4, 0, zero_bytes, stream);

    int nb = (N_NODES + 511) / 512;  // 98
    k_deg_wtrans<<<DEG_BLOCKS + 256 + CAST_BLOCKS, 256, 0, stream>>>(dstv, deg4, rank, W1, W2, WT1, WT2,
                                                                     x, xb);
    k_scan1<<<nb, 512, 0, stream>>>(deg4, rs, partial, dis);
    k_scan23<<<(N_NODES + 255) / 256, 256, 0, stream>>>(rs, partial, nb);
    k_place<<<PLACE_BLOCKS, 256, 0, stream>>>(srcv, dstv, rank, rs, deg4, eidx);

    // layer 1 reassociated: P = Ahat @ X, then Z1 = P@W1 + b1 (+ fused BN stats)
    k_aggr<false><<<(N_NODES * 64 + 255) / 256, 256, 0, stream>>>(xb, dis, nullptr, rs, eidx, P, nullptr);
    dim3 gg1((N_NODES + 255) / 256, C_HID / 64);   // (196, 4)
    k_gemmv<false, 4><<<gg1, 256, 0, stream>>>(P, WT1, z1, nullptr, b1, bnsum, bnsq, nullptr, nullptr,
                                               N_NODES, C_HID);

    // layer 2: g2 = dis * (relu(BN(z1)) @ W2), then out = Ahat-gather + b2
    dim3 gg2((N_NODES + 255) / 256, C_OUT / 64);   // (196, 2)
    k_gemmv<true, 8><<<gg2, 256, 0, stream>>>(z1, WT2, g2, dis, nullptr, bnsum, bnsq, gamma1, beta1,
                                              N_NODES, C_OUT);
    k_aggr<true><<<(N_NODES * 64 + 255) / 256, 256, 0, stream>>>(g2, dis, b2, rs, eidx, nullptr, out);
}

// Round 13
// 241.982 us; speedup vs baseline: 1.0683x; 1.0683x over previous
//
#include <hip/hip_runtime.h>

#define N_NODES 50000
#define N_EDGES 800000
#define C_IN 128
#define C_HID 256
#define C_OUT 128
#define BN_EPS 1e-5f

typedef __bf16 v8bf __attribute__((ext_vector_type(8)));
typedef float f32x4 __attribute__((ext_vector_type(4)));
typedef unsigned short u16x8 __attribute__((ext_vector_type(8)));

// ---------- bf16 helpers (round-to-nearest-even) ----------
static __device__ __forceinline__ unsigned short f2bf(float f) {
    unsigned int u = __float_as_uint(f);
    u += 0x7fffu + ((u >> 16) & 1u);
    return (unsigned short)(u >> 16);
}
static __device__ __forceinline__ float bf2f(unsigned short h) {
    return __uint_as_float((unsigned int)h << 16);
}
static __device__ __forceinline__ unsigned int pack2(float a, float b) {
    return (unsigned int)f2bf(a) | ((unsigned int)f2bf(b) << 16);
}
static __device__ __forceinline__ float lo2f(unsigned int u) { return __uint_as_float(u << 16); }
static __device__ __forceinline__ float hi2f(unsigned int u) { return __uint_as_float(u & 0xffff0000u); }

#define DEG_BLOCKS ((N_EDGES + 255) / 256)
#define CAST_BLOCKS ((N_NODES * 16 + 255) / 256)   // 3125: x -> bf16 cast, 8 floats/thread
#define BN_SLOTS (4 * 196 * 4)                     // GEMM1 panels x blocks x waves = 3136

// ---------------- degree + rank + weight transpose + UNSCALED x cast (fused) ----------
// 800k device-scope atomics: bound by per-atomic memory-side cost (round-9: counter
// splitting neutral), not line contention. The x cast rides the idle BW.

__global__ __launch_bounds__(256) void k_deg_wtrans(const int* __restrict__ dst, int* __restrict__ deg4,
                                                    int* __restrict__ rank,
                                                    const float* __restrict__ W1, const float* __restrict__ W2,
                                                    unsigned short* __restrict__ WT1, unsigned short* __restrict__ WT2,
                                                    const float* __restrict__ x, unsigned short* __restrict__ xb) {
    int bx = blockIdx.x, t = threadIdx.x;
    if (bx < DEG_BLOCKS) {
        int e = bx * 256 + t;
        if (e < N_EDGES) {
            int s = e & 3;
            rank[e] = atomicAdd(&deg4[s * N_NODES + dst[e]], 1);
        }
    } else if (bx < DEG_BLOCKS + 256) {
        int i = (bx - DEG_BLOCKS) * 256 + t;  // [0, 65536)
        if (i < C_IN * C_HID) {               // WT1[n][k] = W1[k][n]
            int n = i >> 7, k = i & 127;
            WT1[n * C_IN + k] = f2bf(W1[k * C_HID + n]);
        } else {
            int j = i - C_IN * C_HID;         // WT2[n][k] = W2[k][n]
            int n = j >> 8, k = j & 255;
            WT2[n * C_HID + k] = f2bf(W2[k * C_OUT + n]);
        }
    } else {
        int i = (bx - DEG_BLOCKS - 256) * 256 + t;
        int node = i >> 4;
        if (node < N_NODES) {
            int g8 = (i & 15) * 8;
            float4 v0 = *(const float4*)&x[(size_t)node * C_IN + g8];
            float4 v1 = *(const float4*)&x[(size_t)node * C_IN + g8 + 4];
            uint4 o = make_uint4(pack2(v0.x, v0.y), pack2(v0.z, v0.w),
                                 pack2(v1.x, v1.y), pack2(v1.z, v1.w));
            *(uint4*)&xb[(size_t)node * C_IN + g8] = o;
        }
    }
}

// ---------------- CSR build ----------------

__global__ __launch_bounds__(512) void k_scan1(int* __restrict__ deg4, int* __restrict__ rs,
                                               int* __restrict__ partial, float* __restrict__ dis) {
    __shared__ int s[512];
    int t = threadIdx.x;
    int i = blockIdx.x * 512 + t;
    int v = 0;
    if (i < N_NODES) {
        int d0 = deg4[i];
        int d1 = deg4[N_NODES + i];
        int d2 = deg4[2 * N_NODES + i];
        int d3 = deg4[3 * N_NODES + i];
        v = d0 + d1 + d2 + d3;
        deg4[N_NODES + i] = d0;
        deg4[2 * N_NODES + i] = d0 + d1;
        deg4[3 * N_NODES + i] = d0 + d1 + d2;
        dis[i] = rsqrtf((float)v + 1.0f);
    }
    s[t] = v;
    __syncthreads();
    for (int off = 1; off < 512; off <<= 1) {
        int tv = (t >= off) ? s[t - off] : 0;
        __syncthreads();
        s[t] += tv;
        __syncthreads();
    }
    if (i < N_NODES) rs[i + 1] = s[t];
    if (t == 511) partial[blockIdx.x] = s[511];
}

// fused scan2+scan3
__global__ __launch_bounds__(256) void k_scan23(int* __restrict__ rs, const int* __restrict__ partial,
                                                int nb) {
    __shared__ int pre[128];
    __shared__ int wsum[2];
    int t = threadIdx.x;
    int lane = t & 63;
    int pv = 0, v = 0;
    if (t < 128) {
        pv = (t < nb) ? partial[t] : 0;
        v = pv;
#pragma unroll
        for (int off = 1; off < 64; off <<= 1) {
            int u = __shfl_up(v, off);
            if (lane >= off) v += u;
        }
        if (lane == 63) wsum[t >> 6] = v;
    }
    __syncthreads();
    if (t < 128) {
        if (t >= 64) v += wsum[0];
        pre[t] = v - pv;
    }
    __syncthreads();
    int i = blockIdx.x * 256 + t;
    if (i < N_NODES) {
        rs[i + 1] = rs[i + 1] + pre[i >> 9];
    }
    if (i == 0) rs[0] = 0;
}

// ---------------- atomic-free CSR placement (split-prefix aware) ----------------

#define PLACE_BLOCKS ((N_EDGES / 4 + 255) / 256)   // 800000/4 lanes of int4

__global__ __launch_bounds__(256) void k_place(const int* __restrict__ src, const int* __restrict__ dst,
                                               const int* __restrict__ rank, const int* __restrict__ rs,
                                               const int* __restrict__ deg4, int* __restrict__ eidx) {
    int q = blockIdx.x * 256 + threadIdx.x;
    int e = q * 4;
    if (e < N_EDGES) {
        int4 d4 = *(const int4*)&dst[e];
        int4 r4 = *(const int4*)&rank[e];
        int4 s4 = *(const int4*)&src[e];
        eidx[rs[d4.x] + r4.x] = s4.x;
        eidx[rs[d4.y] + deg4[N_NODES + d4.y] + r4.y] = s4.y;
        eidx[rs[d4.z] + deg4[2 * N_NODES + d4.z] + r4.z] = s4.z;
        eidx[rs[d4.w] + deg4[3 * N_NODES + d4.w] + r4.w] = s4.w;
    }
}

// ---------------- 128-ch row aggregate: one wave per node (round-7 structure) -------

template <bool FINAL>
__global__ __launch_bounds__(256) void k_aggr(const unsigned short* __restrict__ g,
                                              const float* __restrict__ dis, const float* __restrict__ bias,
                                              const int* __restrict__ rs, const int* __restrict__ eidx,
                                              unsigned short* __restrict__ outb, float* __restrict__ outf) {
    int wid = (blockIdx.x * 256 + threadIdx.x) >> 6;
    int lane = threadIdx.x & 63;
    if (wid >= N_NODES) return;
    int slot = lane >> 4;        // 0..3: which edge of a 4-group
    int cp = lane & 15;          // channel group: 8 ch starting at cp*8
    int s = rs[wid], e = rs[wid + 1];
    float a0 = 0.f, a1 = 0.f, a2 = 0.f, a3 = 0.f, a4 = 0.f, a5 = 0.f, a6 = 0.f, a7 = 0.f;
    int p = s;
    for (; p + 15 < e; p += 16) {
        int i0 = eidx[p + slot];
        int i1 = eidx[p + 4 + slot];
        int i2 = eidx[p + 8 + slot];
        int i3 = eidx[p + 12 + slot];
        u16x8 v0 = *(const u16x8*)&g[(size_t)i0 * 128 + cp * 8];
        u16x8 v1 = *(const u16x8*)&g[(size_t)i1 * 128 + cp * 8];
        u16x8 v2 = *(const u16x8*)&g[(size_t)i2 * 128 + cp * 8];
        u16x8 v3 = *(const u16x8*)&g[(size_t)i3 * 128 + cp * 8];
        if (FINAL) {
            a0 += bf2f(v0[0]) + bf2f(v1[0]) + bf2f(v2[0]) + bf2f(v3[0]);
            a1 += bf2f(v0[1]) + bf2f(v1[1]) + bf2f(v2[1]) + bf2f(v3[1]);
            a2 += bf2f(v0[2]) + bf2f(v1[2]) + bf2f(v2[2]) + bf2f(v3[2]);
            a3 += bf2f(v0[3]) + bf2f(v1[3]) + bf2f(v2[3]) + bf2f(v3[3]);
            a4 += bf2f(v0[4]) + bf2f(v1[4]) + bf2f(v2[4]) + bf2f(v3[4]);
            a5 += bf2f(v0[5]) + bf2f(v1[5]) + bf2f(v2[5]) + bf2f(v3[5]);
            a6 += bf2f(v0[6]) + bf2f(v1[6]) + bf2f(v2[6]) + bf2f(v3[6]);
            a7 += bf2f(v0[7]) + bf2f(v1[7]) + bf2f(v2[7]) + bf2f(v3[7]);
        } else {
            float w0 = dis[i0], w1 = dis[i1], w2 = dis[i2], w3 = dis[i3];
            a0 = fmaf(w0, bf2f(v0[0]), fmaf(w1, bf2f(v1[0]), fmaf(w2, bf2f(v2[0]), fmaf(w3, bf2f(v3[0]), a0))));
            a1 = fmaf(w0, bf2f(v0[1]), fmaf(w1, bf2f(v1[1]), fmaf(w2, bf2f(v2[1]), fmaf(w3, bf2f(v3[1]), a1))));
            a2 = fmaf(w0, bf2f(v0[2]), fmaf(w1, bf2f(v1[2]), fmaf(w2, bf2f(v2[2]), fmaf(w3, bf2f(v3[2]), a2))));
            a3 = fmaf(w0, bf2f(v0[3]), fmaf(w1, bf2f(v1[3]), fmaf(w2, bf2f(v2[3]), fmaf(w3, bf2f(v3[3]), a3))));
            a4 = fmaf(w0, bf2f(v0[4]), fmaf(w1, bf2f(v1[4]), fmaf(w2, bf2f(v2[4]), fmaf(w3, bf2f(v3[4]), a4))));
            a5 = fmaf(w0, bf2f(v0[5]), fmaf(w1, bf2f(v1[5]), fmaf(w2, bf2f(v2[5]), fmaf(w3, bf2f(v3[5]), a5))));
            a6 = fmaf(w0, bf2f(v0[6]), fmaf(w1, bf2f(v1[6]), fmaf(w2, bf2f(v2[6]), fmaf(w3, bf2f(v3[6]), a6))));
            a7 = fmaf(w0, bf2f(v0[7]), fmaf(w1, bf2f(v1[7]), fmaf(w2, bf2f(v2[7]), fmaf(w3, bf2f(v3[7]), a7))));
        }
    }
    if (p < e) {
        int last = e - 1;
        int j0 = p + slot;
        int j1 = j0 + 4;
        int j2 = j0 + 8;
        int j3 = j0 + 12;
        float m0 = (j0 <= last) ? 1.f : 0.f;
        float m1 = (j1 <= last) ? 1.f : 0.f;
        float m2 = (j2 <= last) ? 1.f : 0.f;
        float m3 = (j3 <= last) ? 1.f : 0.f;
        j0 = min(j0, last); j1 = min(j1, last); j2 = min(j2, last); j3 = min(j3, last);
        int i0 = eidx[j0];
        int i1 = eidx[j1];
        int i2 = eidx[j2];
        int i3 = eidx[j3];
        float w0 = m0, w1 = m1, w2 = m2, w3 = m3;
        if (!FINAL) {
            w0 = m0 * dis[i0]; w1 = m1 * dis[i1]; w2 = m2 * dis[i2]; w3 = m3 * dis[i3];
        }
        u16x8 v0 = *(const u16x8*)&g[(size_t)i0 * 128 + cp * 8];
        u16x8 v1 = *(const u16x8*)&g[(size_t)i1 * 128 + cp * 8];
        u16x8 v2 = *(const u16x8*)&g[(size_t)i2 * 128 + cp * 8];
        u16x8 v3 = *(const u16x8*)&g[(size_t)i3 * 128 + cp * 8];
        a0 = fmaf(w0, bf2f(v0[0]), fmaf(w1, bf2f(v1[0]), fmaf(w2, bf2f(v2[0]), fmaf(w3, bf2f(v3[0]), a0))));
        a1 = fmaf(w0, bf2f(v0[1]), fmaf(w1, bf2f(v1[1]), fmaf(w2, bf2f(v2[1]), fmaf(w3, bf2f(v3[1]), a1))));
        a2 = fmaf(w0, bf2f(v0[2]), fmaf(w1, bf2f(v1[2]), fmaf(w2, bf2f(v2[2]), fmaf(w3, bf2f(v3[2]), a2))));
        a3 = fmaf(w0, bf2f(v0[3]), fmaf(w1, bf2f(v1[3]), fmaf(w2, bf2f(v2[3]), fmaf(w3, bf2f(v3[3]), a3))));
        a4 = fmaf(w0, bf2f(v0[4]), fmaf(w1, bf2f(v1[4]), fmaf(w2, bf2f(v2[4]), fmaf(w3, bf2f(v3[4]), a4))));
        a5 = fmaf(w0, bf2f(v0[5]), fmaf(w1, bf2f(v1[5]), fmaf(w2, bf2f(v2[5]), fmaf(w3, bf2f(v3[5]), a5))));
        a6 = fmaf(w0, bf2f(v0[6]), fmaf(w1, bf2f(v1[6]), fmaf(w2, bf2f(v2[6]), fmaf(w3, bf2f(v3[6]), a6))));
        a7 = fmaf(w0, bf2f(v0[7]), fmaf(w1, bf2f(v1[7]), fmaf(w2, bf2f(v2[7]), fmaf(w3, bf2f(v3[7]), a7))));
    }
    a0 += __shfl_xor(a0, 16); a1 += __shfl_xor(a1, 16); a2 += __shfl_xor(a2, 16); a3 += __shfl_xor(a3, 16);
    a4 += __shfl_xor(a4, 16); a5 += __shfl_xor(a5, 16); a6 += __shfl_xor(a6, 16); a7 += __shfl_xor(a7, 16);
    a0 += __shfl_xor(a0, 32); a1 += __shfl_xor(a1, 32); a2 += __shfl_xor(a2, 32); a3 += __shfl_xor(a3, 32);
    a4 += __shfl_xor(a4, 32); a5 += __shfl_xor(a5, 32); a6 += __shfl_xor(a6, 32); a7 += __shfl_xor(a7, 32);
    if (slot < 2) {
        int ch = cp * 8 + slot * 4;
        float r0 = slot ? a4 : a0, r1 = slot ? a5 : a1, r2 = slot ? a6 : a2, r3 = slot ? a7 : a3;
        ushort4 gi = *(const ushort4*)&g[(size_t)wid * 128 + ch];
        float d = dis[wid];
        if (FINAL) {
            float4 bv = *(const float4*)&bias[ch];
            float4 o = make_float4(fmaf(d, r0 + bf2f(gi.x), bv.x), fmaf(d, r1 + bf2f(gi.y), bv.y),
                                   fmaf(d, r2 + bf2f(gi.z), bv.z), fmaf(d, r3 + bf2f(gi.w), bv.w));
            *(float4*)&outf[(size_t)wid * 128 + ch] = o;
        } else {
            float d2 = d * d;   // z = d*a + d^2 * x_d  (x rows unscaled)
            ushort4 z;
            z.x = f2bf(fmaf(d, r0, d2 * bf2f(gi.x)));
            z.y = f2bf(fmaf(d, r1, d2 * bf2f(gi.y)));
            z.z = f2bf(fmaf(d, r2, d2 * bf2f(gi.z)));
            z.w = f2bf(fmaf(d, r3, d2 * bf2f(gi.w)));
            *(ushort4*)&outb[(size_t)wid * 128 + ch] = z;
        }
    }
}

// ---------------- MFMA bf16 GEMM, register-B panels (round-9 structure) ----------------
// Round-12 PMC localized GEMM1's 43us: MfmaUtil 2.6%, occ 18.8%, HBM 12.5%, WRITE = z1
// exactly -> the cost is the BN-stat tail: 400k device-scope atomicAdds onto 512 floats
// (784 serialized RMWs PER CHANNEL). Fix: zero atomics. Each wave writes its 64-ch
// partial (ss/qq) to bnp[slot][64] (slot = (by*196+bx)*4+w, ALL slots written every
// launch -> replay-safe), reduced by k_bnred before GEMM2.

template <bool TRANS, int KC>   // K = KC*32
__global__ __launch_bounds__(256, 2) void k_gemmv(const unsigned short* __restrict__ Ah,
                                                  const unsigned short* __restrict__ BT,
                                                  unsigned short* __restrict__ C,
                                                  const float* __restrict__ dis, const float* __restrict__ bias,
                                                  float* __restrict__ bnp, float* __restrict__ bnsum,
                                                  float* __restrict__ bnsq,
                                                  const float* __restrict__ gamma, const float* __restrict__ beta,
                                                  int M, int N) {
    constexpr int K = KC * 32;
    constexpr int BP = K + 8;                   // B LDS pitch (ushorts); rows 16B-aligned
    __shared__ unsigned short Blds[64 * BP];    // aliased as per-wave C-tiles after extraction
    __shared__ float tsc_s[K];
    __shared__ float tof_s[K];

    int t = threadIdx.x;
    int w = t >> 6, lane = t & 63;
    int lm = lane & 15, quad = lane >> 4;
    int col0 = blockIdx.y * 64;

    if (TRANS && t < K) {
        float inv_n = 1.0f / (float)N_NODES;
        float mu = bnsum[t] * inv_n;
        float var = bnsq[t] * inv_n - mu * mu;
        float a = gamma[t] * rsqrtf(var + BN_EPS);
        tsc_s[t] = a;
        tof_s[t] = beta[t] - mu * a;
    }
    // stage B panel (64 cols x K) to LDS
    constexpr int NLD = 64 * K / 8;
    for (int j = t; j < NLD; j += 256) {
        int n = j / (K / 8);
        int kq = j % (K / 8);
        *(uint4*)&Blds[n * BP + kq * 8] = *(const uint4*)&BT[(size_t)(col0 + n) * K + kq * 8];
    }
    __syncthreads();
    // extract B fragments to registers (row stride BP: 2-way bank alias, free)
    v8bf bfr[4][KC];
#pragma unroll
    for (int in = 0; in < 4; ++in)
#pragma unroll
        for (int kc = 0; kc < KC; ++kc)
            bfr[in][kc] = *(const v8bf*)&Blds[(in * 16 + lm) * BP + kc * 32 + quad * 8];
    __syncthreads();    // B reads done; Blds becomes C-tile scratch

    unsigned short* Ct = Blds + w * (16 * 80);  // per-wave 16x64 tile, pitch 80 (quad-conflict-free)

    float bias_r[4];
    if (!TRANS) {
#pragma unroll
        for (int in = 0; in < 4; ++in) bias_r[in] = bias[col0 + in * 16 + lm];
    }
    float ss[4] = {0.f, 0.f, 0.f, 0.f}, qq[4] = {0.f, 0.f, 0.f, 0.f};

    int strip0 = (blockIdx.x * 4 + w) * 4;
#pragma unroll
    for (int s = 0; s < 4; ++s) {
        int strip = strip0 + s;
        if (strip * 16 >= M) break;             // M is a multiple of 16
        int arow = strip * 16 + lm;
        uint4 araw[KC];
#pragma unroll
        for (int kc = 0; kc < KC; ++kc)
            araw[kc] = *(const uint4*)&Ah[(size_t)arow * K + kc * 32 + quad * 8];
        float dqa[4];
        if (TRANS) *(float4*)dqa = *(const float4*)&dis[strip * 16 + quad * 4];
        f32x4 acc[4] = {};
#pragma unroll
        for (int kc = 0; kc < KC; ++kc) {
            v8bf af;
            if (TRANS) {
                int kb2 = kc * 32 + quad * 8;
                float4 s0 = *(const float4*)&tsc_s[kb2];
                float4 s1 = *(const float4*)&tsc_s[kb2 + 4];
                float4 o0 = *(const float4*)&tof_s[kb2];
                float4 o1 = *(const float4*)&tof_s[kb2 + 4];
                uint4 h = araw[kc];
                float f0 = fmaxf(fmaf(lo2f(h.x), s0.x, o0.x), 0.f);
                float f1 = fmaxf(fmaf(hi2f(h.x), s0.y, o0.y), 0.f);
                float f2 = fmaxf(fmaf(lo2f(h.y), s0.z, o0.z), 0.f);
                float f3 = fmaxf(fmaf(hi2f(h.y), s0.w, o0.w), 0.f);
                float f4 = fmaxf(fmaf(lo2f(h.z), s1.x, o1.x), 0.f);
                float f5 = fmaxf(fmaf(hi2f(h.z), s1.y, o1.y), 0.f);
                float f6 = fmaxf(fmaf(lo2f(h.w), s1.z, o1.z), 0.f);
                float f7 = fmaxf(fmaf(hi2f(h.w), s1.w, o1.w), 0.f);
                uint4 pk = make_uint4(pack2(f0, f1), pack2(f2, f3), pack2(f4, f5), pack2(f6, f7));
                af = *(v8bf*)&pk;
            } else {
                af = *(v8bf*)&araw[kc];
            }
#pragma unroll
            for (int in = 0; in < 4; ++in)
                acc[in] = __builtin_amdgcn_mfma_f32_16x16x32_bf16(af, bfr[in][kc], acc[in], 0, 0, 0);
        }
        // epilogue: pack into per-wave LDS tile (C/D layout: row=quad*4+q, col=in*16+lm)
#pragma unroll
        for (int in = 0; in < 4; ++in) {
#pragma unroll
            for (int q = 0; q < 4; ++q) {
                float val = TRANS ? acc[in][q] * dqa[q] : acc[in][q] + bias_r[in];
                unsigned short hb = f2bf(val);
                Ct[(quad * 4 + q) * 80 + in * 16 + lm] = hb;
                if (!TRANS) {
                    float v = bf2f(hb);
                    ss[in] += v;
                    qq[in] = fmaf(v, v, qq[in]);
                }
            }
        }
        // same-wave LDS round trip (in-order, no barrier) -> coalesced 16B stores
#pragma unroll
        for (int it = 0; it < 2; ++it) {
            int rl = (lane >> 3) + it * 8;
            uint4 v = *(const uint4*)&Ct[rl * 80 + (lane & 7) * 8];
            *(uint4*)&C[(size_t)(strip * 16 + rl) * N + col0 + (lane & 7) * 8] = v;
        }
    }
    if (!TRANS) {
        // per-wave partial BN stats -> global scratch (NO atomics). Wave covers 64
        // channels of panel blockIdx.y; slot fully written even for OOB-strip waves.
        int slot = (blockIdx.y * 196 + blockIdx.x) * 4 + w;
#pragma unroll
        for (int in = 0; in < 4; ++in) {
            float s = ss[in], q2 = qq[in];
            s += __shfl_xor(s, 16); q2 += __shfl_xor(q2, 16);
            s += __shfl_xor(s, 32); q2 += __shfl_xor(q2, 32);
            if (quad == 0) {
                bnp[(size_t)slot * 64 + in * 16 + lm] = s;
                bnp[(size_t)(BN_SLOTS + slot) * 64 + in * 16 + lm] = q2;
            }
        }
    }
}

// ---------------- BN partial reduce: 784 partials per channel, deterministic ----------
// block 0 -> bnsum, block 1 -> bnsq. Channel c: panel p=c>>6, within-panel ci=c&63;
// slots j = p*784 .. p*784+783, addr = (arr*BN_SLOTS + p*784 + j)*64 + ci.

__global__ __launch_bounds__(256) void k_bnred(const float* __restrict__ bnp,
                                               float* __restrict__ bnsum, float* __restrict__ bnsq) {
    int c = threadIdx.x;
    int p = c >> 6, ci = c & 63;
    const float* base = bnp + ((size_t)blockIdx.x * BN_SLOTS + (size_t)p * 784) * 64 + ci;
    float s0 = 0.f, s1 = 0.f, s2 = 0.f, s3 = 0.f;
    for (int j = 0; j < 784; j += 4) {
        s0 += base[(size_t)j * 64];
        s1 += base[(size_t)(j + 1) * 64];
        s2 += base[(size_t)(j + 2) * 64];
        s3 += base[(size_t)(j + 3) * 64];
    }
    float s = (s0 + s1) + (s2 + s3);
    if (blockIdx.x == 0) bnsum[c] = s;
    else bnsq[c] = s;
}

// ---------------- launch ----------------

extern "C" void kernel_launch(void* const* d_in, const int* in_sizes, int n_in,
                              void* d_out, int out_size, void* d_ws, size_t ws_size,
                              hipStream_t stream) {
    const float* x      = (const float*)d_in[0];
    const int*   ei     = (const int*)d_in[1];
    const float* W1     = (const float*)d_in[2];
    const float* b1     = (const float*)d_in[3];
    const float* gamma1 = (const float*)d_in[4];
    const float* beta1  = (const float*)d_in[5];
    const float* W2     = (const float*)d_in[6];
    const float* b2     = (const float*)d_in[7];
    const int* srcv = ei;
    const int* dstv = ei + N_EDGES;
    float* out = (float*)d_out;

    char* w = (char*)d_ws;
    size_t off = 0;
    auto alloc = [&](size_t bytes) {
        void* p = w + off;
        off = (off + bytes + 255) & ~(size_t)255;
        return p;
    };
    int*   deg4    = (int*)alloc((size_t)N_NODES * 4 * 4);   // 4 split counters / prefix offsets
    float* bnsum   = (float*)alloc(256 * 4);
    float* bnsq    = (float*)alloc(256 * 4);
    size_t zero_bytes = off;                           // deg4 + bnsum + bnsq
    float* dis     = (float*)alloc(N_NODES * 4);
    int*   rs      = (int*)alloc((N_NODES + 1) * 4);
    int*   rank    = (int*)alloc((size_t)N_EDGES * 4);
    int*   partial = (int*)alloc(128 * 4);
    int*   eidx    = (int*)alloc((size_t)N_EDGES * 4);
    float* bnp     = (float*)alloc((size_t)2 * BN_SLOTS * 64 * 4);   // per-wave BN partials
    unsigned short* WT1 = (unsigned short*)alloc((size_t)C_IN * C_HID * 2);
    unsigned short* WT2 = (unsigned short*)alloc((size_t)C_HID * C_OUT * 2);
    unsigned short* xb  = (unsigned short*)alloc((size_t)N_NODES * C_IN * 2);
    unsigned short* P   = (unsigned short*)alloc((size_t)N_NODES * C_IN * 2);
    unsigned short* z1  = (unsigned short*)alloc((size_t)N_NODES * C_HID * 2);
    unsigned short* g2  = (unsigned short*)alloc((size_t)N_NODES * C_OUT * 2);
    (void)ws_size; (void)in_sizes; (void)n_in; (void)out_size;

    (void)hipMemsetAsync(deg4, 0, zero_bytes, stream);

    int nb = (N_NODES + 511) / 512;  // 98
    k_deg_wtrans<<<DEG_BLOCKS + 256 + CAST_BLOCKS, 256, 0, stream>>>(dstv, deg4, rank, W1, W2, WT1, WT2,
                                                                     x, xb);
    k_scan1<<<nb, 512, 0, stream>>>(deg4, rs, partial, dis);
    k_scan23<<<(N_NODES + 255) / 256, 256, 0, stream>>>(rs, partial, nb);
    k_place<<<PLACE_BLOCKS, 256, 0, stream>>>(srcv, dstv, rank, rs, deg4, eidx);

    // layer 1 reassociated: P = Ahat @ X, then Z1 = P@W1 + b1 (+ BN partials, atomic-free)
    k_aggr<false><<<(N_NODES * 64 + 255) / 256, 256, 0, stream>>>(xb, dis, nullptr, rs, eidx, P, nullptr);
    dim3 gg1((N_NODES + 255) / 256, C_HID / 64);   // (196, 4)
    k_gemmv<false, 4><<<gg1, 256, 0, stream>>>(P, WT1, z1, nullptr, b1, bnp, bnsum, bnsq,
                                               nullptr, nullptr, N_NODES, C_HID);
    k_bnred<<<2, 256, 0, stream>>>(bnp, bnsum, bnsq);

    // layer 2: g2 = dis * (relu(BN(z1)) @ W2), then out = Ahat-gather + b2
    dim3 gg2((N_NODES + 255) / 256, C_OUT / 64);   // (196, 2)
    k_gemmv<true, 8><<<gg2, 256, 0, stream>>>(z1, WT2, g2, dis, nullptr, bnp, bnsum, bnsq,
                                              gamma1, beta1, N_NODES, C_OUT);
    k_aggr<true><<<(N_NODES * 64 + 255) / 256, 256, 0, stream>>>(g2, dis, b2, rs, eidx, nullptr, out);
}